// Round 3
// baseline (603.083 us; speedup 1.0000x reference)
//
#include <hip/hip_runtime.h>
#include <stdint.h>

// Problem constants
#define N_ 64
#define C_ 64
#define O_ 128
#define T_ 300
#define V_ 25
#define TB 2            // t-groups per block (divides 300)
#define JB (TB * 32)    // 64 padded j-columns (each t padded 25->32)
#define KB 128          // GEMM K: k<64 raw x (residual), k>=64 xa (main)
#define LDB 136         // LDS B row stride in bf16 elements (pad 8 vs 128)
#define SXS 65          // xs row stride in f32 ([50][65] transposed stage)
#define BS_OFF 13056    // bytes: 50*65*4 = 13000, rounded up to 16B multiple
#define SMEM_BYTES (BS_OFF + JB * LDB * 2)  // 13056 + 17408 = 30464 -> 5 blocks/CU
#define STW 1600        // per-wave out-stage floats (32 o x 50)

typedef __attribute__((ext_vector_type(8))) short short8;
typedef __attribute__((ext_vector_type(4))) float floatx4;
typedef __attribute__((ext_vector_type(2))) float floatx2;

__device__ __forceinline__ short f2bf(float f) {
  // round-to-nearest-even fp32 -> bf16 bits
  unsigned u = __float_as_uint(f);
  unsigned r = (u + 0x7FFFu + ((u >> 16) & 1u)) >> 16;
  return (short)(r & 0xFFFFu);
}

// ---------------- prep: fold BN into weights, build M2 = A*edge, bias table ----
__global__ void sgc_prep(const float* __restrict__ A, const float* __restrict__ edge,
                         const float* __restrict__ gcn_w, const float* __restrict__ gcn_b,
                         const float* __restrict__ bn_g, const float* __restrict__ bn_b,
                         const float* __restrict__ bn_m, const float* __restrict__ bn_v,
                         const float* __restrict__ res_w, const float* __restrict__ res_b,
                         const float* __restrict__ rg, const float* __restrict__ rb,
                         const float* __restrict__ rm, const float* __restrict__ rv,
                         short* __restrict__ Wcat, float* __restrict__ M2p,
                         float* __restrict__ Cwp) {
  const int tid = threadIdx.x;
  // M2p[v][w], stride 32, pad cols w>=25 are 0
  for (int i = tid; i < 25 * 32; i += 256) {
    const int v = i >> 5, w = i & 31;
    M2p[i] = (w < 25) ? A[v * 25 + w] * edge[v * 25 + w] : 0.f;
  }
  // Cw[o][w] = inv1*gcn_b*S[w] + (bn_b - bn_m*inv1) + inv2*res_b + (rb - rm*inv2)
  for (int i = tid; i < O_ * 32; i += 256) {
    const int o = i >> 5, w = i & 31;
    const float inv1 = bn_g[o] * rsqrtf(bn_v[o] + 1e-5f);
    const float inv2 = rg[o] * rsqrtf(rv[o] + 1e-5f);
    float S = 0.f;
    if (w < 25) {
      for (int v = 0; v < 25; ++v) S += A[v * 25 + w] * edge[v * 25 + w];
    }
    Cwp[i] = inv1 * gcn_b[o] * S + (bn_b[o] - bn_m[o] * inv1) + inv2 * res_b[o] +
             (rb[o] - rm[o] * inv2);
  }
  // Wcat bf16 [o][k]: k<64 -> inv2*res_w (raw x rows), k>=64 -> inv1*gcn_w (xa rows)
  for (int i = tid; i < O_ * KB; i += 256) {
    const int o = i >> 7, k = i & 127;
    const float inv1 = bn_g[o] * rsqrtf(bn_v[o] + 1e-5f);
    const float inv2 = rg[o] * rsqrtf(rv[o] + 1e-5f);
    const float val = (k < 64) ? inv2 * res_w[o * 64 + k] : inv1 * gcn_w[o * 64 + (k - 64)];
    Wcat[i] = f2bf(val);
  }
}

// ---------------- main fused kernel -------------------------------------------
// grid: 64 n * 150 t-blocks; block: 256 threads (4 waves); 5 blocks/CU (LDS-limited)
__global__ __launch_bounds__(256, 4) void sgc_main(const float* __restrict__ x,
                                                   const short* __restrict__ Wcat,
                                                   const float* __restrict__ M2p,
                                                   const float* __restrict__ Cw,
                                                   float* __restrict__ out) {
  __shared__ __align__(16) char smem[SMEM_BYTES];
  float* const xs = (float*)smem;               // phase 1: [p=tl*25+v][c] f32, stride SXS
  short* const Bs = (short*)(smem + BS_OFF);    // [j][k] bf16, stride LDB

  const int tid = threadIdx.x;
  const int b = blockIdx.x;
  const int n = b / 150;
  const int t0 = (b % 150) * TB;
  const int lane = tid & 63;
  const int wv = tid >> 6;
  const int l15 = lane & 15;
  const int quad = lane >> 4;
  const int obase = wv * 32;  // each wave: 32 o-rows (2 M-tiles) x all 64 j

  // A-frags hoisted: global (L1/L2-hot) loads overlap phase-1 latency.
  short8 af[2][4];
#pragma unroll
  for (int mt = 0; mt < 2; ++mt) {
#pragma unroll
    for (int kq = 0; kq < 4; ++kq) {
      af[mt][kq] =
          *(const short8*)(Wcat + (obase + mt * 16 + l15) * KB + kq * 32 + quad * 8);
    }
  }

  // ---- phase 1a: coalesced float2 global reads -> transposed f32 LDS stage ----
  // x slice: per c, 50 contiguous floats (t0,t0+1 x 25v); 8B-aligned (t0*25 even).
  {
    const float* xbase = x + n * (C_ * T_ * V_) + t0 * V_;
    for (int u = tid; u < 1600; u += 256) {        // 64 c * 25 float2-chunks
      const int c = u / 25;
      const int q = u - c * 25;
      const floatx2 vv = *(const floatx2*)(xbase + c * (T_ * V_) + q * 2);
      const int a0 = (q * 2) * SXS + c;
      xs[a0] = vv[0];
      xs[a0 + SXS] = vv[1];
    }
    // NOTE: no j-pad zeroing needed — pad j-columns of D are never stored, and
    // MFMA B-columns are independent (garbage stays confined to discarded cols).
  }
  __syncthreads();

  // ---- phase 1b: per-(c,t) row from LDS: raw bf16 + xa = row @ M2 -> bf16 ----
  // All 4 waves active: tid -> (c, tl, h); h splits the 25-wide w/v range 0..12 / 12..24
  // (w=12 written by both halves with bit-identical values — benign).
  {
    const int c = tid & 63;
    const int tl = (tid >> 6) & 1;
    const int h = tid >> 7;
    const int w0 = h * 12;      // h=0: 0..12, h=1: 12..24 (13 each)
    float xr[25];
#pragma unroll
    for (int v = 0; v < 25; ++v) xr[v] = xs[(tl * 25 + v) * SXS + c];
    // raw x rows: B[j = tl*32+v][k = c]
#pragma unroll
    for (int i = 0; i < 13; ++i) Bs[(tl * 32 + w0 + i) * LDB + c] = f2bf(xr[w0 + i]);
    // xa_c[w] = sum_v x[c,t,v] * M2[v][w]  (M2 reads wave-uniform)
    float xa[13];
#pragma unroll
    for (int i = 0; i < 13; ++i) xa[i] = 0.f;
    for (int v = 0; v < 25; ++v) {
      const float xv = xr[v];
      const float* m2 = M2p + v * 32 + w0;
#pragma unroll
      for (int i = 0; i < 13; ++i) xa[i] = __builtin_fmaf(xv, m2[i], xa[i]);
    }
    // xa rows: B[j = tl*32+w][k = 64+c]
#pragma unroll
    for (int i = 0; i < 13; ++i) Bs[(tl * 32 + w0 + i) * LDB + 64 + c] = f2bf(xa[i]);
  }
  __syncthreads();

  // ---- phase 2: MFMA  D[o][j] = Wcat[o][k] * B[k][j] ----
  floatx4 acc[2][4];
#pragma unroll
  for (int mt = 0; mt < 2; ++mt)
#pragma unroll
    for (int jt = 0; jt < 4; ++jt) acc[mt][jt] = (floatx4){0.f, 0.f, 0.f, 0.f};

#pragma unroll
  for (int jt = 0; jt < 4; ++jt) {
#pragma unroll
    for (int kq = 0; kq < 4; ++kq) {
      // B-frag: B[k=quad*8+jj][j] -> 16 contiguous bf16 from LDS
      const short8 bf =
          *(const short8*)(&Bs[(jt * 16 + l15) * LDB + kq * 32 + quad * 8]);
      acc[0][jt] = __builtin_amdgcn_mfma_f32_16x16x32_bf16(af[0][kq], bf, acc[0][jt], 0, 0, 0);
      acc[1][jt] = __builtin_amdgcn_mfma_f32_16x16x32_bf16(af[1][kq], bf, acc[1][jt], 0, 0, 0);
    }
  }
  __syncthreads();  // all waves done reading Bs; smem reused as per-wave out stage

  // ---- epilogue: + Cw, relu -> per-wave LDS stage (32 o x 50) ----
  // C/D layout: col=l15 -> j, row=quad*4+r -> o. Stage is wave-private.
  {
    float* const st = (float*)smem + wv * STW;
#pragma unroll
    for (int mt = 0; mt < 2; ++mt) {
#pragma unroll
      for (int jt = 0; jt < 4; ++jt) {
        const int j = jt * 16 + l15;
        const int w = j & 31;
        if (w < 25) {
          const int tloc = j >> 5;
          const int ol0 = mt * 16 + quad * 4;             // o within wave's 32
          const float* cwp = Cw + (obase + ol0) * 32 + w;
          float* sp = st + ol0 * 50 + tloc * 25 + w;
#pragma unroll
          for (int r = 0; r < 4; ++r) {
            const float val = acc[mt][jt][r] + cwp[r * 32];
            sp[r * 50] = val > 0.f ? val : 0.f;
          }
        }
      }
    }
  }
  // stage is wave-private: wave-lockstep LDS only needs the write drained, no barrier
  asm volatile("s_waitcnt lgkmcnt(0)" ::: "memory");

  // ---- coalesced float2 stores: per wave, 32 o-chunks of 200 contiguous B ----
  {
    float* const st = (float*)smem + wv * STW;
    float* const ob = out + ((n * O_ + obase) * T_ + t0) * V_;
    for (int u = lane; u < 800; u += 64) {   // 32 o * 25 float2
      const int ol = u / 25;
      const int q = u - ol * 25;
      *(floatx2*)(ob + ol * (T_ * V_) + q * 2) = *(const floatx2*)(st + ol * 50 + q * 2);
    }
  }
}

extern "C" void kernel_launch(void* const* d_in, const int* in_sizes, int n_in,
                              void* d_out, int out_size, void* d_ws, size_t ws_size,
                              hipStream_t stream) {
  const float* x = (const float*)d_in[0];
  const float* A = (const float*)d_in[1];
  const float* edge = (const float*)d_in[2];
  const float* gcn_w = (const float*)d_in[3];
  const float* gcn_b = (const float*)d_in[4];
  const float* bn_g = (const float*)d_in[5];
  const float* bn_b = (const float*)d_in[6];
  const float* bn_m = (const float*)d_in[7];
  const float* bn_v = (const float*)d_in[8];
  const float* res_w = (const float*)d_in[9];
  const float* res_b = (const float*)d_in[10];
  const float* rg = (const float*)d_in[11];
  const float* rb = (const float*)d_in[12];
  const float* rm = (const float*)d_in[13];
  const float* rv = (const float*)d_in[14];

  char* ws = (char*)d_ws;
  short* Wcat = (short*)(ws);          // 32768 B
  float* M2p = (float*)(ws + 32768);   // 3200 B
  float* Cwp = (float*)(ws + 36864);   // 16384 B
  float* out = (float*)d_out;

  hipLaunchKernelGGL(sgc_prep, dim3(1), dim3(256), 0, stream, A, edge, gcn_w, gcn_b,
                     bn_g, bn_b, bn_m, bn_v, res_w, res_b, rg, rb, rm, rv, Wcat, M2p, Cwp);
  hipLaunchKernelGGL(sgc_main, dim3(N_ * (T_ / TB)), dim3(256), 0, stream, x, Wcat, M2p,
                     Cwp, out);
}

// Round 4
// 489.032 us; speedup vs baseline: 1.2332x; 1.2332x over previous
//
#include <hip/hip_runtime.h>
#include <stdint.h>

// Problem constants
#define N_ 64
#define C_ 64
#define O_ 128
#define T_ 300
#define V_ 25
#define TB 4            // t-groups per block (divides 300)
#define JB (TB * 32)    // 128 padded j-columns (each t padded 25->32)
#define KB 128          // GEMM K: k<64 raw x (residual), k>=64 xa (main)
#define LDB 136         // LDS B row stride in bf16 elements (272 B: 16B-aligned rows, 2-way-max b128 reads)

typedef __attribute__((ext_vector_type(8))) short short8;
typedef __attribute__((ext_vector_type(4))) float floatx4;

__device__ __forceinline__ short f2bf(float f) {
  // round-to-nearest-even fp32 -> bf16 bits
  unsigned u = __float_as_uint(f);
  unsigned r = (u + 0x7FFFu + ((u >> 16) & 1u)) >> 16;
  return (short)(r & 0xFFFFu);
}
__device__ __forceinline__ float bf2f(short h) {
  return __uint_as_float(((unsigned)(unsigned short)h) << 16);
}

// ---------------- prep: fold BN into weights, M2^T MFMA-frag table, bias table ----
// M2f layout: [(wh*2 + hilo)*64 + lane]*8 + jj  (bf16), wh = w-half (0: w0..15, 1: w16..31)
//   entry = M2[v = (lane>>4)*8 + jj][w = wh*16 + (lane&15)], hi = bf16(m), lo = bf16(m - hi)
__global__ void sgc_prep(const float* __restrict__ A, const float* __restrict__ edge,
                         const float* __restrict__ gcn_w, const float* __restrict__ gcn_b,
                         const float* __restrict__ bn_g, const float* __restrict__ bn_b,
                         const float* __restrict__ bn_m, const float* __restrict__ bn_v,
                         const float* __restrict__ res_w, const float* __restrict__ res_b,
                         const float* __restrict__ rg, const float* __restrict__ rb,
                         const float* __restrict__ rm, const float* __restrict__ rv,
                         short* __restrict__ Wcat, short* __restrict__ M2f,
                         float* __restrict__ Cwp) {
  const int tid = threadIdx.x;
  // M2^T fragment table (2 wh x 2 hilo x 64 lanes x 8 jj = 2048 bf16)
  for (int i = tid; i < 2048; i += 256) {
    const int wh = i >> 10;
    const int hl = (i >> 9) & 1;
    const int ln = (i >> 3) & 63;
    const int jj = i & 7;
    const int v = ((ln >> 4) << 3) + jj;
    const int w = wh * 16 + (ln & 15);
    float m = (v < 25 && w < 25) ? A[v * 25 + w] * edge[v * 25 + w] : 0.f;
    const short h = f2bf(m);
    M2f[i] = hl ? f2bf(m - bf2f(h)) : h;
  }
  // Cw[o][w] = inv1*gcn_b*S[w] + (bn_b - bn_m*inv1) + inv2*res_b + (rb - rm*inv2)
  for (int i = tid; i < O_ * 32; i += 256) {
    const int o = i >> 5, w = i & 31;
    const float inv1 = bn_g[o] * rsqrtf(bn_v[o] + 1e-5f);
    const float inv2 = rg[o] * rsqrtf(rv[o] + 1e-5f);
    float S = 0.f;
    if (w < 25) {
      for (int v = 0; v < 25; ++v) S += A[v * 25 + w] * edge[v * 25 + w];
    }
    Cwp[i] = inv1 * gcn_b[o] * S + (bn_b[o] - bn_m[o] * inv1) + inv2 * res_b[o] +
             (rb[o] - rm[o] * inv2);
  }
  // Wcat bf16 [o][k]: k<64 -> inv2*res_w (raw x rows), k>=64 -> inv1*gcn_w (xa rows)
  for (int i = tid; i < O_ * KB; i += 256) {
    const int o = i >> 7, k = i & 127;
    const float inv1 = bn_g[o] * rsqrtf(bn_v[o] + 1e-5f);
    const float inv2 = rg[o] * rsqrtf(rv[o] + 1e-5f);
    const float val = (k < 64) ? inv2 * res_w[o * 64 + k] : inv1 * gcn_w[o * 64 + (k - 64)];
    Wcat[i] = f2bf(val);
  }
}

// ---------------- main fused kernel -------------------------------------------
// grid: 64 n * 75 t-blocks; block: 256 threads (4 waves); ONE barrier.
// Phase 1 (per wave = one t): lane (quad,l15) loads x[c=ct*16+l15][t][v=quad*8..]
//   -> raw bf16 into Bs[j=(t,v)][k=c]; xa via 3 compensated MFMAs (K=32, M2f B-frags)
//   -> ds_write_b64 into Bs[j=(t,w)][k=64+c'].
// Phase 2: D[o][j] = Wcat[o][k] * Bs[j][k], direct relu+bias stores (R0-proven).
__global__ __launch_bounds__(256, 3) void sgc_main(const float* __restrict__ x,
                                                   const short* __restrict__ Wcat,
                                                   const short* __restrict__ M2f,
                                                   const float* __restrict__ Cw,
                                                   float* __restrict__ out) {
  __shared__ __align__(16) short Bs[JB * LDB];  // 128 x 136 bf16 = 34816 B
  const int tid = threadIdx.x;
  const int b = blockIdx.x;
  const int n = b / 75;
  const int t0 = (b % 75) * TB;
  const int lane = tid & 63;
  const int wv = tid >> 6;
  const int l15 = lane & 15;
  const int quad = lane >> 4;
  const int obase = wv * 32;  // phase 2: each wave 32 o-rows x all 128 j

  // A-frags (Wcat, L2-hot) hoisted to overlap phase-1 latency
  short8 af[2][4];
#pragma unroll
  for (int mt = 0; mt < 2; ++mt) {
#pragma unroll
    for (int kq = 0; kq < 4; ++kq) {
      af[mt][kq] =
          *(const short8*)(Wcat + (obase + mt * 16 + l15) * KB + kq * 32 + quad * 8);
    }
  }

  // ---- phase 1: x loads + raw staging + MFMA-based xa ----
  {
    const int t = wv;  // wave's local t
    // M2^T frags
    const short8 m2hi0 = *(const short8*)(M2f + ((0 * 2 + 0) * 64 + lane) * 8);
    const short8 m2lo0 = *(const short8*)(M2f + ((0 * 2 + 1) * 64 + lane) * 8);
    const short8 m2hi1 = *(const short8*)(M2f + ((1 * 2 + 0) * 64 + lane) * 8);
    const short8 m2lo1 = *(const short8*)(M2f + ((1 * 2 + 1) * 64 + lane) * 8);

    short8 xhi[4], xlo[4];
    const float* xq = x + ((n * C_ + l15) * T_ + (t0 + t)) * V_ + quad * 8;
#pragma unroll
    for (int ct = 0; ct < 4; ++ct) {
      const float* xp = xq + ct * 16 * (T_ * V_);
      float xv[8];
      if (quad < 3) {
#pragma unroll
        for (int i = 0; i < 8; ++i) xv[i] = xp[i];
      } else {
        xv[0] = xp[0];  // v=24 (last real); v=25..31 padded 0 (M2f rows also 0)
#pragma unroll
        for (int i = 1; i < 8; ++i) xv[i] = 0.f;
      }
      short8 h, l;
#pragma unroll
      for (int i = 0; i < 8; ++i) {
        const short hb = f2bf(xv[i]);
        h[i] = hb;
        l[i] = f2bf(xv[i] - bf2f(hb));
      }
      xhi[ct] = h;
      xlo[ct] = l;
      // raw x rows: Bs[j = t*32 + v][k = c], v = quad*8 + i
      short* bp = Bs + (t * 32 + quad * 8) * LDB + ct * 16 + l15;
      if (quad < 3) {
#pragma unroll
        for (int i = 0; i < 8; ++i) bp[i * LDB] = h[i];
      } else {
        bp[0] = h[0];
      }
    }

    // xa[c][w] = sum_v x[c][v] * M2[v][w], compensated: x_hi*M2_hi + x_lo*M2_hi + x_hi*M2_lo
    // D layout: row = quad*4 + r -> c (within ct*16 tile), col = l15 -> w (within wh*16)
#pragma unroll
    for (int ct = 0; ct < 4; ++ct) {
#pragma unroll
      for (int wh = 0; wh < 2; ++wh) {
        floatx4 a = (floatx4){0.f, 0.f, 0.f, 0.f};
        a = __builtin_amdgcn_mfma_f32_16x16x32_bf16(xhi[ct], wh ? m2hi1 : m2hi0, a, 0, 0, 0);
        a = __builtin_amdgcn_mfma_f32_16x16x32_bf16(xlo[ct], wh ? m2hi1 : m2hi0, a, 0, 0, 0);
        a = __builtin_amdgcn_mfma_f32_16x16x32_bf16(xhi[ct], wh ? m2lo1 : m2lo0, a, 0, 0, 0);
        // pack 4 bf16 (k = 64 + ct*16 + quad*4 + r) -> aligned 8B LDS write
        const unsigned d0 = ((unsigned)(unsigned short)f2bf(a[1]) << 16) |
                            (unsigned short)f2bf(a[0]);
        const unsigned d1 = ((unsigned)(unsigned short)f2bf(a[3]) << 16) |
                            (unsigned short)f2bf(a[2]);
        unsigned* wp =
            (unsigned*)(Bs + (t * 32 + wh * 16 + l15) * LDB + 64 + ct * 16 + quad * 4);
        wp[0] = d0;
        wp[1] = d1;
      }
    }
  }
  __syncthreads();

  // ---- phase 2: MFMA  D[o][j] = Wcat[o][k] * B[k][j] ----
  floatx4 acc[2][8];
#pragma unroll
  for (int mt = 0; mt < 2; ++mt)
#pragma unroll
    for (int jt = 0; jt < 8; ++jt) acc[mt][jt] = (floatx4){0.f, 0.f, 0.f, 0.f};

#pragma unroll
  for (int jt = 0; jt < 8; ++jt) {
#pragma unroll
    for (int kq = 0; kq < 4; ++kq) {
      const short8 bf =
          *(const short8*)(&Bs[(jt * 16 + l15) * LDB + kq * 32 + quad * 8]);
      acc[0][jt] = __builtin_amdgcn_mfma_f32_16x16x32_bf16(af[0][kq], bf, acc[0][jt], 0, 0, 0);
      acc[1][jt] = __builtin_amdgcn_mfma_f32_16x16x32_bf16(af[1][kq], bf, acc[1][jt], 0, 0, 0);
    }
  }

  // ---- epilogue: + Cw, relu, store (C/D: col=l15 -> j, row=quad*4+r -> o) ----
#pragma unroll
  for (int mt = 0; mt < 2; ++mt) {
#pragma unroll
    for (int jt = 0; jt < 8; ++jt) {
      const int j = jt * 16 + l15;
      const int w = j & 31;
      if (w < 25) {
        const int tloc = j >> 5;
        const int o0 = obase + mt * 16 + quad * 4;
        float* op = out + (((n * O_ + o0) * T_) + (t0 + tloc)) * V_ + w;
        const float* cwp = Cw + o0 * 32 + w;
#pragma unroll
        for (int r = 0; r < 4; ++r) {
          const float val = acc[mt][jt][r] + cwp[r * 32];
          op[r * (T_ * V_)] = val > 0.f ? val : 0.f;
        }
      }
    }
  }
}

extern "C" void kernel_launch(void* const* d_in, const int* in_sizes, int n_in,
                              void* d_out, int out_size, void* d_ws, size_t ws_size,
                              hipStream_t stream) {
  const float* x = (const float*)d_in[0];
  const float* A = (const float*)d_in[1];
  const float* edge = (const float*)d_in[2];
  const float* gcn_w = (const float*)d_in[3];
  const float* gcn_b = (const float*)d_in[4];
  const float* bn_g = (const float*)d_in[5];
  const float* bn_b = (const float*)d_in[6];
  const float* bn_m = (const float*)d_in[7];
  const float* bn_v = (const float*)d_in[8];
  const float* res_w = (const float*)d_in[9];
  const float* res_b = (const float*)d_in[10];
  const float* rg = (const float*)d_in[11];
  const float* rb = (const float*)d_in[12];
  const float* rm = (const float*)d_in[13];
  const float* rv = (const float*)d_in[14];

  char* ws = (char*)d_ws;
  short* Wcat = (short*)(ws);          // 32768 B
  short* M2f = (short*)(ws + 32768);   // 4096 B (2048 bf16)
  float* Cwp = (float*)(ws + 36864);   // 16384 B
  float* out = (float*)d_out;

  hipLaunchKernelGGL(sgc_prep, dim3(1), dim3(256), 0, stream, A, edge, gcn_w, gcn_b,
                     bn_g, bn_b, bn_m, bn_v, res_w, res_b, rg, rb, rm, rv, Wcat, M2f, Cwp);
  hipLaunchKernelGGL(sgc_main, dim3(N_ * (T_ / TB)), dim3(256), 0, stream, x, Wcat, M2f,
                     Cwp, out);
}